// Round 14
// baseline (699.479 us; speedup 1.0000x reference)
//
#include <hip/hip_runtime.h>
#include <hip/hip_bf16.h>
#include <cstdint>
#include <cstddef>

#define BB   4
#define SS   1024
#define DD   768
#define HH   4
#define DQ   192
#define DFF  3072
#define NVOC 30522
#define NPAD 30592    // 239 * 128 (unused for vocab now)
#define NPAD2 30720   // 120 * 256 (vocab wide-tile padding)

typedef __attribute__((ext_vector_type(8))) short bf16x8;
typedef __attribute__((ext_vector_type(4))) float f32x4;
#define AS1 __attribute__((address_space(1)))
#define AS3 __attribute__((address_space(3)))

static __device__ __forceinline__ float bf2f(short s) {
  union { unsigned int u; float f; } v; v.u = ((unsigned int)(unsigned short)s) << 16; return v.f;
}
static __device__ __forceinline__ short f2bf(float f) {
  union { float f; unsigned int u; } v; v.f = f;
  unsigned int r = v.u + 0x7FFFu + ((v.u >> 16) & 1u);   // round-to-nearest-even
  if ((v.u & 0x7F800000u) == 0x7F800000u) r = v.u;       // inf/nan: truncate
  return (short)(r >> 16);
}

// ==================== embedding + LayerNorm -> xb (bf16) ====================
__global__ __launch_bounds__(256) void k_embed_ln(
    const int* __restrict__ ids, const float* __restrict__ tok,
    const float* __restrict__ seg, const float* __restrict__ pos,
    const float* __restrict__ g, const float* __restrict__ bta,
    short* __restrict__ xb)
{
  int row = blockIdx.x;           // b*S + s
  int s = row & (SS - 1);
  int id = ids[row];
  int t = threadIdx.x;
  const float* tp = tok + (size_t)id * DD;
  const float* sp = seg + (size_t)id * DD;
  const float* pp = pos + (size_t)s * DD;
  float v[3];
  float sum = 0.f;
#pragma unroll
  for (int j = 0; j < 3; ++j) {
    int d = t + j * 256;
    v[j] = tp[d] + sp[d] + pp[d];
    sum += v[j];
  }
  __shared__ float red[4];
#pragma unroll
  for (int w = 1; w < 64; w <<= 1) sum += __shfl_xor(sum, w);
  int wid = t >> 6, lane = t & 63;
  if (lane == 0) red[wid] = sum;
  __syncthreads();
  float mu = (red[0] + red[1] + red[2] + red[3]) * (1.f / DD);
  float vs = 0.f;
#pragma unroll
  for (int j = 0; j < 3; ++j) { float d2 = v[j] - mu; vs += d2 * d2; }
#pragma unroll
  for (int w = 1; w < 64; w <<= 1) vs += __shfl_xor(vs, w);
  __syncthreads();
  if (lane == 0) red[wid] = vs;
  __syncthreads();
  float var = (red[0] + red[1] + red[2] + red[3]) * (1.f / DD);
  float rstd = rsqrtf(var + 1e-5f);
#pragma unroll
  for (int j = 0; j < 3; ++j) {
    int d = t + j * 256;
    float val = (v[j] - mu) * rstd * g[d] + bta[d];
    xb[(size_t)row * DD + d] = f2bf(val);
  }
}

// ==================== pack QKV weights -> Btqkv[2304][768] bf16 ====================
__global__ __launch_bounds__(256) void k_packqkv(
    const float* __restrict__ Wq, const float* __restrict__ Wk,
    const float* __restrict__ Wv, short* __restrict__ Bt)
{
  __shared__ float tile[32][33];
  int dq0 = blockIdx.x * 32;            // 0..160 within head
  int k0  = blockIdx.y * 32;
  int z   = blockIdx.z;                 // mat*4 + h
  int mat = z >> 2, h = z & 3;
  const float* W = mat == 0 ? Wq : (mat == 1 ? Wk : Wv);
  int tx = threadIdx.x & 31, ty = threadIdx.x >> 5;
#pragma unroll
  for (int j = 0; j < 4; ++j) {
    int kk = ty + j * 8;
    tile[kk][tx] = W[((size_t)h * DD + k0 + kk) * DQ + dq0 + tx];
  }
  __syncthreads();
#pragma unroll
  for (int j = 0; j < 4; ++j) {
    int r = ty + j * 8;                 // local dq
    Bt[(size_t)(mat * DD + h * DQ + dq0 + r) * DD + k0 + tx] = f2bf(tile[tx][r]);
  }
}

__global__ void k_bpack(const float* __restrict__ bq, const float* __restrict__ bk,
                        const float* __restrict__ bv, float* __restrict__ out)
{
  int t = blockIdx.x * 256 + threadIdx.x;
  if (t >= 3 * DD) return;
  out[t] = (t < DD) ? bq[t] : (t < 2 * DD ? bk[t - DD] : bv[t - 2 * DD]);
}

// ==================== generic f32[K][N] -> bf16 Bt[Npad][K] transpose ==============
__global__ __launch_bounds__(256) void k_wtrans(
    const float* __restrict__ W, short* __restrict__ Bt, int N, int K)
{
  __shared__ float tile[32][33];
  int n0 = blockIdx.x * 32, k0 = blockIdx.y * 32;
  int tx = threadIdx.x & 31, ty = threadIdx.x >> 5;
#pragma unroll
  for (int j = 0; j < 4; ++j) {
    int kk = ty + j * 8;
    tile[kk][tx] = (n0 + tx < N) ? W[(size_t)(k0 + kk) * N + n0 + tx] : 0.f;
  }
  __syncthreads();
#pragma unroll
  for (int j = 0; j < 4; ++j) {
    int r = ty + j * 8;
    Bt[(size_t)(n0 + r) * K + k0 + tx] = f2bf(tile[tx][r]);
  }
}

// ==================== V section of qkvb -> vt[768][4096] bf16 ======================
__global__ __launch_bounds__(256) void k_vtrans(
    const short* __restrict__ qkvb, short* __restrict__ vt)
{
  __shared__ short tile[32][33];
  int s0 = blockIdx.x * 32, d0 = blockIdx.y * 32;
  int tx = threadIdx.x & 31, ty = threadIdx.x >> 5;
#pragma unroll
  for (int j = 0; j < 4; ++j) {
    int kk = ty + j * 8;
    tile[kk][tx] = qkvb[(size_t)(s0 + kk) * 2304 + 2 * DD + d0 + tx];
  }
  __syncthreads();
#pragma unroll
  for (int j = 0; j < 4; ++j) {
    int r = ty + j * 8;
    vt[(size_t)(d0 + r) * (BB * SS) + s0 + tx] = tile[tx][r];
  }
}

// ==================== bf16 MFMA GEMM 128x128, BK=32, 3-buffer ring =================
template <int OUTBF, int RELU>
__global__ __launch_bounds__(256) void k_gemm_bf16(
    const short* __restrict__ A,    // [4096][K] bf16
    const short* __restrict__ Bt,   // [Ntiles*128][K] bf16 (row = output col)
    const float* __restrict__ bias, void* __restrict__ Cout,
    int N, int K, int NT)
{
  __shared__ alignas(16) short As[3][128 * 32];
  __shared__ alignas(16) short Bs[3][128 * 32];

  int bid = blockIdx.x;
  int xcd = bid & 7;
  int c   = bid >> 3;
  int tm  = xcd * 4 + (c & 3);  // 0..31
  int tn  = c >> 2;             // 0..NT-1
  int m0 = tm * 128, n0 = tn * 128;

  int t = threadIdx.x;
  int w = t >> 6, l = t & 63;
  int fr = l & 15, fq = l >> 4;
  int wr = w >> 1, wc = w & 1;

  auto STAGE = [&](int buf, int kt) {
    int k0 = kt * 32;
#pragma unroll
    for (int i = 0; i < 2; ++i) {
      int G = i * 256 + t;
      int row = G >> 2, gc = G & 3;
      int cs = gc ^ ((row & 7) >> 1);
      const short* gA = &A[(size_t)(m0 + row) * K + k0 + cs * 8];
      const short* gB = &Bt[(size_t)(n0 + row) * K + k0 + cs * 8];
      __builtin_amdgcn_global_load_lds((const AS1 void*)gA, (AS3 void*)&As[buf][G * 8], 16, 0, 0);
      __builtin_amdgcn_global_load_lds((const AS1 void*)gB, (AS3 void*)&Bs[buf][G * 8], 16, 0, 0);
    }
  };

  f32x4 acc[4][4];
#pragma unroll
  for (int i = 0; i < 4; ++i)
#pragma unroll
    for (int j = 0; j < 4; ++j)
      acc[i][j] = (f32x4){0.f, 0.f, 0.f, 0.f};

  int nk = K >> 5;
  STAGE(0, 0);
  STAGE(1, 1);
  int buf = 0;
  for (int kt = 0; kt < nk; ++kt) {
    if (kt + 2 < nk) {
      STAGE((buf + 2) % 3, kt + 2);
      asm volatile("s_waitcnt vmcnt(8)" ::: "memory");
    } else if (kt + 1 < nk) {
      asm volatile("s_waitcnt vmcnt(4)" ::: "memory");
    } else {
      asm volatile("s_waitcnt vmcnt(0)" ::: "memory");
    }
    __builtin_amdgcn_s_barrier();
    const short* Acur = &As[buf][0];
    const short* Bcur = &Bs[buf][0];
    bf16x8 af[4], bfr[4];
    int slot = fq ^ ((fr & 7) >> 1);
#pragma unroll
    for (int mi = 0; mi < 4; ++mi) {
      int row = wr * 64 + mi * 16 + fr;
      af[mi] = *(const bf16x8*)&Acur[row * 32 + slot * 8];
    }
#pragma unroll
    for (int nj = 0; nj < 4; ++nj) {
      int row = wc * 64 + nj * 16 + fr;
      bfr[nj] = *(const bf16x8*)&Bcur[row * 32 + slot * 8];
    }
#pragma unroll
    for (int mi = 0; mi < 4; ++mi)
#pragma unroll
      for (int nj = 0; nj < 4; ++nj)
        acc[mi][nj] = __builtin_amdgcn_mfma_f32_16x16x32_bf16(af[mi], bfr[nj], acc[mi][nj], 0, 0, 0);
    __builtin_amdgcn_s_barrier();
    buf = (buf + 1) % 3;
  }

#pragma unroll
  for (int nj = 0; nj < 4; ++nj) {
    int col = n0 + wc * 64 + nj * 16 + fr;
    if (col < N) {
      float bv = bias[col];
#pragma unroll
      for (int mi = 0; mi < 4; ++mi) {
#pragma unroll
        for (int rg = 0; rg < 4; ++rg) {
          int row = m0 + wr * 64 + mi * 16 + fq * 4 + rg;
          float v = acc[mi][nj][rg] + bv;
          if (RELU) v = fmaxf(v, 0.f);
          if (OUTBF) ((short*)Cout)[(size_t)row * N + col] = f2bf(v);
          else       ((float*)Cout)[(size_t)row * N + col] = v;
        }
      }
    }
  }
}

// ==================== vocab GEMM: 128x256 tile, 8 waves, BK=32 ring-3 ==============
// Same skeleton/proofs as k_gemm_bf16; B-side staging halves per output.
__global__ __launch_bounds__(512) void k_gemm_wide(
    const short* __restrict__ A,    // [4096][768] bf16
    const short* __restrict__ Bt,   // [30720][768] bf16 (row = output col)
    const float* __restrict__ bias, float* __restrict__ C, int N, int K)
{
  __shared__ alignas(16) short As[3][128 * 32];
  __shared__ alignas(16) short Bs[3][256 * 32];

  int bid = blockIdx.x;           // 3840 = 8 xcd * 480
  int xcd = bid & 7;
  int c   = bid >> 3;             // 0..479
  int tm  = xcd * 4 + (c & 3);    // 0..31
  int tn  = c >> 2;               // 0..119
  int m0 = tm * 128, n0 = tn * 256;

  int t = threadIdx.x;
  int w = t >> 6, l = t & 63;
  int fr = l & 15, fq = l >> 4;
  int wr = w >> 2, wc = w & 3;    // 2M x 4N waves; per-wave out 64x64

  auto STAGE = [&](int buf, int kt) {
    int k0 = kt * 32;
    {
      int G = t;                  // A: 512 granules, 1/thread
      int row = G >> 2, gc = G & 3;
      int cs = gc ^ ((row & 7) >> 1);
      __builtin_amdgcn_global_load_lds((const AS1 void*)&A[(size_t)(m0 + row) * K + k0 + cs * 8],
                                       (AS3 void*)&As[buf][G * 8], 16, 0, 0);
    }
#pragma unroll
    for (int i = 0; i < 2; ++i) { // B: 1024 granules, 2/thread
      int G = i * 512 + t;
      int row = G >> 2, gc = G & 3;
      int cs = gc ^ ((row & 7) >> 1);
      __builtin_amdgcn_global_load_lds((const AS1 void*)&Bt[(size_t)(n0 + row) * K + k0 + cs * 8],
                                       (AS3 void*)&Bs[buf][G * 8], 16, 0, 0);
    }
  };

  f32x4 acc[4][4];
#pragma unroll
  for (int i = 0; i < 4; ++i)
#pragma unroll
    for (int j = 0; j < 4; ++j)
      acc[i][j] = (f32x4){0.f, 0.f, 0.f, 0.f};

  int nk = K >> 5;                // 24
  STAGE(0, 0);
  STAGE(1, 1);
  int buf = 0;
  for (int kt = 0; kt < nk; ++kt) {
    if (kt + 2 < nk) {
      STAGE((buf + 2) % 3, kt + 2);
      asm volatile("s_waitcnt vmcnt(6)" ::: "memory");   // 3/thread/step in flight x2
    } else if (kt + 1 < nk) {
      asm volatile("s_waitcnt vmcnt(3)" ::: "memory");
    } else {
      asm volatile("s_waitcnt vmcnt(0)" ::: "memory");
    }
    __builtin_amdgcn_s_barrier();
    const short* Acur = &As[buf][0];
    const short* Bcur = &Bs[buf][0];
    bf16x8 af[4], bfr[4];
    int slot = fq ^ ((fr & 7) >> 1);
#pragma unroll
    for (int mi = 0; mi < 4; ++mi) {
      int row = wr * 64 + mi * 16 + fr;
      af[mi] = *(const bf16x8*)&Acur[row * 32 + slot * 8];
    }
#pragma unroll
    for (int nj = 0; nj < 4; ++nj) {
      int row = wc * 64 + nj * 16 + fr;
      bfr[nj] = *(const bf16x8*)&Bcur[row * 32 + slot * 8];
    }
#pragma unroll
    for (int mi = 0; mi < 4; ++mi)
#pragma unroll
      for (int nj = 0; nj < 4; ++nj)
        acc[mi][nj] = __builtin_amdgcn_mfma_f32_16x16x32_bf16(af[mi], bfr[nj], acc[mi][nj], 0, 0, 0);
    __builtin_amdgcn_s_barrier();
    buf = (buf + 1) % 3;
  }

#pragma unroll
  for (int nj = 0; nj < 4; ++nj) {
    int col = n0 + wc * 64 + nj * 16 + fr;
    if (col < N) {
      float bv = bias[col];
#pragma unroll
      for (int mi = 0; mi < 4; ++mi) {
#pragma unroll
        for (int rg = 0; rg < 4; ++rg) {
          int row = m0 + wr * 64 + mi * 16 + fq * 4 + rg;
          C[(size_t)row * N + col] = acc[mi][nj][rg] + bv;
        }
      }
    }
  }
}

// ==================== staged bf16 MFMA flash attention, kv-split x2, T13 defer-max ====
__global__ __launch_bounds__(256) void k_attn(
    const short* __restrict__ qkvb,   // [4096][2304] bf16 (q|k|v)
    const short* __restrict__ vt,     // [768][4096] bf16
    const unsigned char* __restrict__ mask,
    float* __restrict__ opart,        // [2][4096][768] f32 (unnormalized O)
    float* __restrict__ mlws)         // [2][4096][4][2] f32 (m,l per row,head)
{
  __shared__ short KsS[64 * 192];
  __shared__ short VtS[192 * 64];
  __shared__ short PsS[4 * 16 * 72];
  __shared__ unsigned char MsB[64 * 64];

  int bid = blockIdx.x;
  int x    = bid & 7;
  int r_   = bid >> 3;
  int bh   = x * 2 + (r_ & 1);
  int rest = r_ >> 1;
  int qt   = rest & 15;
  int kvh  = rest >> 4;
  int b = bh >> 2, h = bh & 3;
  int q0 = qt * 64;
  int t = threadIdx.x;
  int wq = t >> 6, l = t & 63;
  int fr = l & 15, fq = l >> 4;
  int qrow = q0 + wq * 16;

  bf16x8 qf[6];
#pragma unroll
  for (int dc = 0; dc < 6; ++dc)
    qf[dc] = *(const bf16x8*)&qkvb[(size_t)(b * SS + qrow + fr) * 2304 + h * DQ + dc * 32 + fq * 8];

  f32x4 cacc[12];
#pragma unroll
  for (int i = 0; i < 12; ++i) cacc[i] = (f32x4){0.f, 0.f, 0.f, 0.f};
  float m_r[4] = {-INFINITY, -INFINITY, -INFINITY, -INFINITY};
  float l_r[4] = {0.f, 0.f, 0.f, 0.f};

  short* myPs = &PsS[wq * 1152];

  for (int kt = kvh * 8; kt < kvh * 8 + 8; ++kt) {
    int kv0 = kt * 64;
    __syncthreads();
#pragma unroll
    for (int i = 0; i < 6; ++i) {
      int g = i * 256 + t;
      int kv = g / 24, cc = g % 24;
      int cs = cc ^ (kv & 7);
      const short* gp = &qkvb[(size_t)(b * SS + kv0 + kv) * 2304 + DD + h * DQ + cs * 8];
      __builtin_amdgcn_global_load_lds((const AS1 void*)gp, (AS3 void*)&KsS[g * 8], 16, 0, 0);
    }
#pragma unroll
    for (int i = 0; i < 6; ++i) {
      int g = i * 256 + t;
      int d = g >> 3, cc = g & 7;
      int cs = cc ^ (d & 7);
      const short* gp = &vt[(size_t)(h * DQ + d) * (BB * SS) + b * SS + kv0 + cs * 8];
      __builtin_amdgcn_global_load_lds((const AS1 void*)gp, (AS3 void*)&VtS[g * 8], 16, 0, 0);
    }
    {
      int q = t >> 2, c16 = t & 3;
      const unsigned char* gp = mask + (size_t)b * SS * SS + (size_t)(q0 + q) * SS + kv0 + c16 * 16;
      __builtin_amdgcn_global_load_lds((const AS1 void*)gp, (AS3 void*)&MsB[t * 16], 16, 0, 0);
    }
    __syncthreads();

    f32x4 s[4];
#pragma unroll
    for (int nt = 0; nt < 4; ++nt) s[nt] = (f32x4){0.f, 0.f, 0.f, 0.f};
#pragma unroll
    for (int dc = 0; dc < 6; ++dc) {
#pragma unroll
      for (int nt = 0; nt < 4; ++nt) {
        int row = nt * 16 + fr;
        int wby = (dc * 64 + fq * 16) ^ ((fr & 7) << 4);
        bf16x8 kf = *(const bf16x8*)&KsS[row * 192 + (wby >> 1)];
        s[nt] = __builtin_amdgcn_mfma_f32_16x16x32_bf16(qf[dc], kf, s[nt], 0, 0, 0);
      }
    }

    float smat[4][4];
#pragma unroll
    for (int rg = 0; rg < 4; ++rg)
#pragma unroll
      for (int nt = 0; nt < 4; ++nt) {
        float v = s[nt][rg] * (1.f / 32.f);
        if (MsB[(wq * 16 + fq * 4 + rg) * 64 + nt * 16 + fr]) v = -1e9f;
        smat[nt][rg] = v;
      }

    float svm[4];
    int ok = 1;
#pragma unroll
    for (int rg = 0; rg < 4; ++rg) {
      svm[rg] = fmaxf(fmaxf(smat[0][rg], smat[1][rg]), fmaxf(smat[2][rg], smat[3][rg]));
      ok &= (svm[rg] <= m_r[rg] + 8.f) ? 1 : 0;
    }
    float p[4][4];
    if (__all(ok)) {
#pragma unroll
      for (int rg = 0; rg < 4; ++rg)
#pragma unroll
        for (int nt = 0; nt < 4; ++nt) {
          float pv = expf(smat[nt][rg] - m_r[rg]);
          p[nt][rg] = pv;
          l_r[rg] += pv;
        }
    } else {
#pragma unroll
      for (int rg = 0; rg < 4; ++rg) {
        float mx = svm[rg];
#pragma unroll
        for (int w2 = 1; w2 < 16; w2 <<= 1) mx = fmaxf(mx, __shfl_xor(mx, w2));
        float mnew = fmaxf(m_r[rg], mx);
        float alpha = expf(m_r[rg] - mnew);
        l_r[rg] *= alpha;
#pragma unroll
        for (int nt = 0; nt < 4; ++nt) {
          float pv = expf(smat[nt][rg] - mnew);
          p[nt][rg] = pv;
          l_r[rg] += pv;
        }
#pragma unroll
        for (int nt = 0; nt < 12; ++nt) cacc[nt][rg] *= alpha;
        m_r[rg] = mnew;
      }
    }

#pragma unroll
    for (int nt = 0; nt < 4; ++nt)
#pragma unroll
      for (int rg = 0; rg < 4; ++rg)
        myPs[(fq * 4 + rg) * 72 + nt * 16 + fr] = f2bf(p[nt][rg]);
    asm volatile("s_waitcnt lgkmcnt(0)" ::: "memory");

    bf16x8 pa[2];
#pragma unroll
    for (int kc = 0; kc < 2; ++kc)
      pa[kc] = *(const bf16x8*)&myPs[fr * 72 + kc * 32 + fq * 8];
#pragma unroll
    for (int nt = 0; nt < 12; ++nt) {
      int row = nt * 16 + fr;
#pragma unroll
      for (int kc = 0; kc < 2; ++kc) {
        int wby = (kc * 64 + fq * 16) ^ ((fr & 7) << 4);
        bf16x8 vf = *(const bf16x8*)&VtS[row * 64 + (wby >> 1)];
        cacc[nt] = __builtin_amdgcn_mfma_f32_16x16x32_bf16(pa[kc], vf, cacc[nt], 0, 0, 0);
      }
    }
  }

#pragma unroll
  for (int rg = 0; rg < 4; ++rg) {
    float ls = l_r[rg];
#pragma unroll
    for (int w2 = 1; w2 < 16; w2 <<= 1) ls += __shfl_xor(ls, w2);
    l_r[rg] = ls;
  }

  float* op = opart + (size_t)kvh * (BB * SS * DD);
#pragma unroll
  for (int rg = 0; rg < 4; ++rg) {
    int row = b * SS + qrow + fq * 4 + rg;
    if (fr == 0) {
      mlws[(((size_t)kvh * (BB * SS) + row) * 4 + h) * 2 + 0] = m_r[rg];
      mlws[(((size_t)kvh * (BB * SS) + row) * 4 + h) * 2 + 1] = l_r[rg];
    }
#pragma unroll
    for (int nt = 0; nt < 12; ++nt)
      op[(size_t)row * DD + h * DQ + nt * 16 + fr] = cacc[nt][rg];
  }
}

// ==================== flash-merge of the two kv halves ====================
__global__ __launch_bounds__(256) void k_amerge(
    const float* __restrict__ opart, const float* __restrict__ mlws,
    short* __restrict__ ctxb)
{
  int row = blockIdx.x;
  int t = threadIdx.x;
  __shared__ float a0s[4], a1s[4], linvs[4];
  if (t < 4) {
    float m0 = mlws[(((size_t)row) * 4 + t) * 2 + 0];
    float l0 = mlws[(((size_t)row) * 4 + t) * 2 + 1];
    float m1 = mlws[(((size_t)(BB * SS) + row) * 4 + t) * 2 + 0];
    float l1 = mlws[(((size_t)(BB * SS) + row) * 4 + t) * 2 + 1];
    float m = fmaxf(m0, m1);
    float a0 = expf(m0 - m), a1 = expf(m1 - m);
    a0s[t] = a0; a1s[t] = a1;
    linvs[t] = 1.f / (l0 * a0 + l1 * a1);
  }
  __syncthreads();
#pragma unroll
  for (int j = 0; j < 3; ++j) {
    int d = t + j * 256;
    int h = d / DQ;
    float o0 = opart[(size_t)row * DD + d];
    float o1 = opart[(size_t)(BB * SS) * DD + (size_t)row * DD + d];
    ctxb[(size_t)row * DD + d] = f2bf((o0 * a0s[h] + o1 * a1s[h]) * linvs[h]);
  }
}

// ==================== cls head from bf16 ff (f32 weights/accum) ====================
__global__ void k_cls(const short* __restrict__ ffb, const float* __restrict__ Wc,
                      const float* __restrict__ bc, float* __restrict__ out)
{
  int t = threadIdx.x;
  int o = t >> 3, l8 = t & 7;
  int b = o >> 1, cN = o & 1;
  float s = 0.f;
  for (int d = l8; d < DD; d += 8)
    s += bf2f(ffb[(size_t)(b * SS) * DD + d]) * Wc[d * 2 + cN];
#pragma unroll
  for (int w = 1; w < 8; w <<= 1) s += __shfl_xor(s, w);
  if (l8 == 0) out[o] = s + bc[cN];
}

// ==========================================================================
extern "C" void kernel_launch(void* const* d_in, const int* in_sizes, int n_in,
                              void* d_out, int out_size, void* d_ws, size_t ws_size,
                              hipStream_t stream)
{
  const int*           ids  = (const int*)d_in[0];
  const unsigned char* mask = (const unsigned char*)d_in[1];
  const float* tok  = (const float*)d_in[2];
  const float* seg  = (const float*)d_in[3];
  const float* pos  = (const float*)d_in[4];
  const float* ln_g = (const float*)d_in[5];
  const float* ln_b = (const float*)d_in[6];
  const float* Wq   = (const float*)d_in[7];
  const float* bq   = (const float*)d_in[8];
  const float* Wk   = (const float*)d_in[9];
  const float* bk   = (const float*)d_in[10];
  const float* Wv   = (const float*)d_in[11];
  const float* bv   = (const float*)d_in[12];
  const float* Wo   = (const float*)d_in[13];
  const float* bo   = (const float*)d_in[14];
  const float* W1   = (const float*)d_in[15];
  const float* b1   = (const float*)d_in[16];
  const float* W2   = (const float*)d_in[17];
  const float* b2   = (const float*)d_in[18];
  const float* Wtok = (const float*)d_in[19];
  const float* btok = (const float*)d_in[20];
  const float* Wcls = (const float*)d_in[21];
  const float* bcls = (const float*)d_in[22];

  // -------- workspace regions (float units), aliasing by lifetime --------
  float* ws = (float*)d_ws;
  short* qkvb = (short*)(ws);                          // [4096][2304] bf16, [0, 4718592)
  short* Bt1  = (short*)(ws);                          // [3072][768]  bf16 (step 7)
  short* ff1b = (short*)(ws + 1310720);                // [4096][3072] bf16 (step 7)
  short* Btt  = (short*)(ws);                          // [30720][768] bf16 (step 9; 11,796,480 floats,
                                                       //  overlaps dead Bt2 head + dead vt head — both done by step 9)
  float* opart = ws + 4718592;                         // [2][4096][768] f32 (attn only)
  float* mlws  = ws + 4718592 + 6291456;               // [2][4096][4][2] f32
  short* vt   = (short*)(ws + 11747328);               // [768][4096] bf16
  short* Btwo = (short*)(ws + 11747328);
  short* Bt2  = (short*)(ws + 11747328);
  short* ctxb = (short*)(ws + 13320192);               // [4096][768] bf16
  short* ffb  = (short*)(ws + 13320192);
  short* xb   = (short*)(ws + 14893056);               // [4096][768] bf16
  short* attb = (short*)(ws + 14893056);
  short* Btqkv = (short*)(ws + 16465920);              // [2304][768] bf16
  float* bqkv = ws + 17350656;

  float* cls    = (float*)d_out;
  float* tokout = (float*)d_out + 8;

  // 1. embeddings + LayerNorm
  k_embed_ln<<<BB * SS, 256, 0, stream>>>(ids, tok, seg, pos, ln_g, ln_b, xb);

  // 2. QKV weight pack + bias pack
  k_packqkv<<<dim3(6, 24, 12), 256, 0, stream>>>(Wq, Wk, Wv, Btqkv);
  k_bpack<<<9, 256, 0, stream>>>(bq, bk, bv, bqkv);

  // 3. fused QKV GEMM -> qkvb bf16 [4096][2304]
  k_gemm_bf16<1, 0><<<8 * 4 * 18, 256, 0, stream>>>(xb, Btqkv, bqkv, qkvb, 2304, DD, 18);

  // 4. V transpose -> vt [768][4096]
  k_vtrans<<<dim3(128, 24), 256, 0, stream>>>(qkvb, vt);

  // 5. wide MFMA attention (kv-split x2) + merge -> ctxb
  k_attn<<<512, 256, 0, stream>>>(qkvb, vt, mask, opart, mlws);
  k_amerge<<<BB * SS, 256, 0, stream>>>(opart, mlws, ctxb);

  // 6. Wo GEMM -> attb
  k_wtrans<<<dim3(24, 24), 256, 0, stream>>>(Wo, Btwo, DD, DD);
  k_gemm_bf16<1, 0><<<8 * 4 * 6, 256, 0, stream>>>(ctxb, Btwo, bo, attb, DD, DD, 6);

  // 7. FFN
  k_wtrans<<<dim3(96, 24), 256, 0, stream>>>(W1, Bt1, DFF, DD);
  k_gemm_bf16<1, 1><<<8 * 4 * 24, 256, 0, stream>>>(attb, Bt1, b1, ff1b, DFF, DD, 24);
  k_wtrans<<<dim3(24, 96), 256, 0, stream>>>(W2, Bt2, DD, DFF);
  k_gemm_bf16<1, 0><<<8 * 4 * 6, 256, 0, stream>>>(ff1b, Bt2, b2, ffb, DD, DFF, 6);

  // 8. cls head (bf16 ff, f32 weights/accum)
  k_cls<<<1, 64, 0, stream>>>(ffb, Wcls, bcls, cls);

  // 9. vocab projection: Wtok -> Btt [30720][768], then 128x256 ring-3 GEMM
  k_wtrans<<<dim3(NPAD2 / 32, 24), 256, 0, stream>>>(Wtok, Btt, NVOC, DD);
  k_gemm_wide<<<8 * 480, 512, 0, stream>>>(ffb, Btt, btok, tokout, NVOC, DD);
}

// Round 16
// 665.414 us; speedup vs baseline: 1.0512x; 1.0512x over previous
//
#include <hip/hip_runtime.h>
#include <hip/hip_bf16.h>
#include <cstdint>
#include <cstddef>

#define BB   4
#define SS   1024
#define DD   768
#define HH   4
#define DQ   192
#define DFF  3072
#define NVOC 30522
#define NPAD 30592   // 239 * 128

typedef __attribute__((ext_vector_type(8))) short bf16x8;
typedef __attribute__((ext_vector_type(4))) float f32x4;
#define AS1 __attribute__((address_space(1)))
#define AS3 __attribute__((address_space(3)))

static __device__ __forceinline__ float bf2f(short s) {
  union { unsigned int u; float f; } v; v.u = ((unsigned int)(unsigned short)s) << 16; return v.f;
}
static __device__ __forceinline__ short f2bf(float f) {
  union { float f; unsigned int u; } v; v.f = f;
  unsigned int r = v.u + 0x7FFFu + ((v.u >> 16) & 1u);   // round-to-nearest-even
  if ((v.u & 0x7F800000u) == 0x7F800000u) r = v.u;       // inf/nan: truncate
  return (short)(r >> 16);
}

// ==================== embedding + LayerNorm -> xb (bf16) ====================
__global__ __launch_bounds__(256) void k_embed_ln(
    const int* __restrict__ ids, const float* __restrict__ tok,
    const float* __restrict__ seg, const float* __restrict__ pos,
    const float* __restrict__ g, const float* __restrict__ bta,
    short* __restrict__ xb)
{
  int row = blockIdx.x;           // b*S + s
  int s = row & (SS - 1);
  int id = ids[row];
  int t = threadIdx.x;
  const float* tp = tok + (size_t)id * DD;
  const float* sp = seg + (size_t)id * DD;
  const float* pp = pos + (size_t)s * DD;
  float v[3];
  float sum = 0.f;
#pragma unroll
  for (int j = 0; j < 3; ++j) {
    int d = t + j * 256;
    v[j] = tp[d] + sp[d] + pp[d];
    sum += v[j];
  }
  __shared__ float red[4];
#pragma unroll
  for (int w = 1; w < 64; w <<= 1) sum += __shfl_xor(sum, w);
  int wid = t >> 6, lane = t & 63;
  if (lane == 0) red[wid] = sum;
  __syncthreads();
  float mu = (red[0] + red[1] + red[2] + red[3]) * (1.f / DD);
  float vs = 0.f;
#pragma unroll
  for (int j = 0; j < 3; ++j) { float d2 = v[j] - mu; vs += d2 * d2; }
#pragma unroll
  for (int w = 1; w < 64; w <<= 1) vs += __shfl_xor(vs, w);
  __syncthreads();
  if (lane == 0) red[wid] = vs;
  __syncthreads();
  float var = (red[0] + red[1] + red[2] + red[3]) * (1.f / DD);
  float rstd = rsqrtf(var + 1e-5f);
#pragma unroll
  for (int j = 0; j < 3; ++j) {
    int d = t + j * 256;
    float val = (v[j] - mu) * rstd * g[d] + bta[d];
    xb[(size_t)row * DD + d] = f2bf(val);
  }
}

// ==================== pack QKV weights -> Btqkv[2304][768] bf16 ====================
__global__ __launch_bounds__(256) void k_packqkv(
    const float* __restrict__ Wq, const float* __restrict__ Wk,
    const float* __restrict__ Wv, short* __restrict__ Bt)
{
  __shared__ float tile[32][33];
  int dq0 = blockIdx.x * 32;            // 0..160 within head
  int k0  = blockIdx.y * 32;
  int z   = blockIdx.z;                 // mat*4 + h
  int mat = z >> 2, h = z & 3;
  const float* W = mat == 0 ? Wq : (mat == 1 ? Wk : Wv);
  int tx = threadIdx.x & 31, ty = threadIdx.x >> 5;
#pragma unroll
  for (int j = 0; j < 4; ++j) {
    int kk = ty + j * 8;
    tile[kk][tx] = W[((size_t)h * DD + k0 + kk) * DQ + dq0 + tx];
  }
  __syncthreads();
#pragma unroll
  for (int j = 0; j < 4; ++j) {
    int r = ty + j * 8;                 // local dq
    Bt[(size_t)(mat * DD + h * DQ + dq0 + r) * DD + k0 + tx] = f2bf(tile[tx][r]);
  }
}

__global__ void k_bpack(const float* __restrict__ bq, const float* __restrict__ bk,
                        const float* __restrict__ bv, float* __restrict__ out)
{
  int t = blockIdx.x * 256 + threadIdx.x;
  if (t >= 3 * DD) return;
  out[t] = (t < DD) ? bq[t] : (t < 2 * DD ? bk[t - DD] : bv[t - 2 * DD]);
}

// ==================== generic f32[K][N] -> bf16 Bt[Npad][K] transpose ==============
__global__ __launch_bounds__(256) void k_wtrans(
    const float* __restrict__ W, short* __restrict__ Bt, int N, int K)
{
  __shared__ float tile[32][33];
  int n0 = blockIdx.x * 32, k0 = blockIdx.y * 32;
  int tx = threadIdx.x & 31, ty = threadIdx.x >> 5;
#pragma unroll
  for (int j = 0; j < 4; ++j) {
    int kk = ty + j * 8;
    tile[kk][tx] = (n0 + tx < N) ? W[(size_t)(k0 + kk) * N + n0 + tx] : 0.f;
  }
  __syncthreads();
#pragma unroll
  for (int j = 0; j < 4; ++j) {
    int r = ty + j * 8;
    Bt[(size_t)(n0 + r) * K + k0 + tx] = f2bf(tile[tx][r]);
  }
}

// ==================== V section of qkvb -> vt[768][4096] bf16 ======================
__global__ __launch_bounds__(256) void k_vtrans(
    const short* __restrict__ qkvb, short* __restrict__ vt)
{
  __shared__ short tile[32][33];
  int s0 = blockIdx.x * 32, d0 = blockIdx.y * 32;
  int tx = threadIdx.x & 31, ty = threadIdx.x >> 5;
#pragma unroll
  for (int j = 0; j < 4; ++j) {
    int kk = ty + j * 8;
    tile[kk][tx] = qkvb[(size_t)(s0 + kk) * 2304 + 2 * DD + d0 + tx];
  }
  __syncthreads();
#pragma unroll
  for (int j = 0; j < 4; ++j) {
    int r = ty + j * 8;
    vt[(size_t)(d0 + r) * (BB * SS) + s0 + tx] = tile[tx][r];
  }
}

// ==================== bf16 MFMA GEMM 128x128, BK=32, 3-buffer ring (r13-proven) ====
// + T5 setprio around the MFMA cluster (scheduler hint only).
template <int OUTBF, int RELU>
__global__ __launch_bounds__(256) void k_gemm_bf16(
    const short* __restrict__ A,    // [4096][K] bf16
    const short* __restrict__ Bt,   // [Ntiles*128][K] bf16 (row = output col)
    const float* __restrict__ bias, void* __restrict__ Cout,
    int N, int K, int NT)
{
  __shared__ alignas(16) short As[3][128 * 32];
  __shared__ alignas(16) short Bs[3][128 * 32];

  int bid = blockIdx.x;
  int xcd = bid & 7;
  int c   = bid >> 3;
  int tm  = xcd * 4 + (c & 3);  // 0..31
  int tn  = c >> 2;             // 0..NT-1
  int m0 = tm * 128, n0 = tn * 128;

  int t = threadIdx.x;
  int w = t >> 6, l = t & 63;
  int fr = l & 15, fq = l >> 4;
  int wr = w >> 1, wc = w & 1;

  auto STAGE = [&](int buf, int kt) {
    int k0 = kt * 32;
#pragma unroll
    for (int i = 0; i < 2; ++i) {
      int G = i * 256 + t;
      int row = G >> 2, gc = G & 3;
      int cs = gc ^ ((row & 7) >> 1);
      const short* gA = &A[(size_t)(m0 + row) * K + k0 + cs * 8];
      const short* gB = &Bt[(size_t)(n0 + row) * K + k0 + cs * 8];
      __builtin_amdgcn_global_load_lds((const AS1 void*)gA, (AS3 void*)&As[buf][G * 8], 16, 0, 0);
      __builtin_amdgcn_global_load_lds((const AS1 void*)gB, (AS3 void*)&Bs[buf][G * 8], 16, 0, 0);
    }
  };

  f32x4 acc[4][4];
#pragma unroll
  for (int i = 0; i < 4; ++i)
#pragma unroll
    for (int j = 0; j < 4; ++j)
      acc[i][j] = (f32x4){0.f, 0.f, 0.f, 0.f};

  int nk = K >> 5;
  STAGE(0, 0);
  STAGE(1, 1);
  int buf = 0;
  for (int kt = 0; kt < nk; ++kt) {
    if (kt + 2 < nk) {
      STAGE((buf + 2) % 3, kt + 2);
      asm volatile("s_waitcnt vmcnt(8)" ::: "memory");
    } else if (kt + 1 < nk) {
      asm volatile("s_waitcnt vmcnt(4)" ::: "memory");
    } else {
      asm volatile("s_waitcnt vmcnt(0)" ::: "memory");
    }
    __builtin_amdgcn_s_barrier();
    const short* Acur = &As[buf][0];
    const short* Bcur = &Bs[buf][0];
    bf16x8 af[4], bfr[4];
    int slot = fq ^ ((fr & 7) >> 1);
#pragma unroll
    for (int mi = 0; mi < 4; ++mi) {
      int row = wr * 64 + mi * 16 + fr;
      af[mi] = *(const bf16x8*)&Acur[row * 32 + slot * 8];
    }
#pragma unroll
    for (int nj = 0; nj < 4; ++nj) {
      int row = wc * 64 + nj * 16 + fr;
      bfr[nj] = *(const bf16x8*)&Bcur[row * 32 + slot * 8];
    }
    __builtin_amdgcn_s_setprio(1);
#pragma unroll
    for (int mi = 0; mi < 4; ++mi)
#pragma unroll
      for (int nj = 0; nj < 4; ++nj)
        acc[mi][nj] = __builtin_amdgcn_mfma_f32_16x16x32_bf16(af[mi], bfr[nj], acc[mi][nj], 0, 0, 0);
    __builtin_amdgcn_s_setprio(0);
    __builtin_amdgcn_s_barrier();
    buf = (buf + 1) % 3;
  }

#pragma unroll
  for (int nj = 0; nj < 4; ++nj) {
    int col = n0 + wc * 64 + nj * 16 + fr;
    if (col < N) {
      float bv = bias[col];
#pragma unroll
      for (int mi = 0; mi < 4; ++mi) {
#pragma unroll
        for (int rg = 0; rg < 4; ++rg) {
          int row = m0 + wr * 64 + mi * 16 + fq * 4 + rg;
          float v = acc[mi][nj][rg] + bv;
          if (RELU) v = fmaxf(v, 0.f);
          if (OUTBF) ((short*)Cout)[(size_t)row * N + col] = f2bf(v);
          else       ((float*)Cout)[(size_t)row * N + col] = v;
        }
      }
    }
  }
}

// ==================== staged bf16 MFMA flash attention, kv-split x2, T13 defer-max ====
__global__ __launch_bounds__(256) void k_attn(
    const short* __restrict__ qkvb,   // [4096][2304] bf16 (q|k|v)
    const short* __restrict__ vt,     // [768][4096] bf16
    const unsigned char* __restrict__ mask,
    float* __restrict__ opart,        // [2][4096][768] f32 (unnormalized O)
    float* __restrict__ mlws)         // [2][4096][4][2] f32 (m,l per row,head)
{
  __shared__ short KsS[64 * 192];
  __shared__ short VtS[192 * 64];
  __shared__ short PsS[4 * 16 * 72];
  __shared__ unsigned char MsB[64 * 64];

  int bid = blockIdx.x;
  int x    = bid & 7;
  int r_   = bid >> 3;
  int bh   = x * 2 + (r_ & 1);
  int rest = r_ >> 1;
  int qt   = rest & 15;
  int kvh  = rest >> 4;
  int b = bh >> 2, h = bh & 3;
  int q0 = qt * 64;
  int t = threadIdx.x;
  int wq = t >> 6, l = t & 63;
  int fr = l & 15, fq = l >> 4;
  int qrow = q0 + wq * 16;

  bf16x8 qf[6];
#pragma unroll
  for (int dc = 0; dc < 6; ++dc)
    qf[dc] = *(const bf16x8*)&qkvb[(size_t)(b * SS + qrow + fr) * 2304 + h * DQ + dc * 32 + fq * 8];

  f32x4 cacc[12];
#pragma unroll
  for (int i = 0; i < 12; ++i) cacc[i] = (f32x4){0.f, 0.f, 0.f, 0.f};
  float m_r[4] = {-INFINITY, -INFINITY, -INFINITY, -INFINITY};
  float l_r[4] = {0.f, 0.f, 0.f, 0.f};

  short* myPs = &PsS[wq * 1152];

  for (int kt = kvh * 8; kt < kvh * 8 + 8; ++kt) {
    int kv0 = kt * 64;
    __syncthreads();
#pragma unroll
    for (int i = 0; i < 6; ++i) {
      int g = i * 256 + t;
      int kv = g / 24, cc = g % 24;
      int cs = cc ^ (kv & 7);
      const short* gp = &qkvb[(size_t)(b * SS + kv0 + kv) * 2304 + DD + h * DQ + cs * 8];
      __builtin_amdgcn_global_load_lds((const AS1 void*)gp, (AS3 void*)&KsS[g * 8], 16, 0, 0);
    }
#pragma unroll
    for (int i = 0; i < 6; ++i) {
      int g = i * 256 + t;
      int d = g >> 3, cc = g & 7;
      int cs = cc ^ (d & 7);
      const short* gp = &vt[(size_t)(h * DQ + d) * (BB * SS) + b * SS + kv0 + cs * 8];
      __builtin_amdgcn_global_load_lds((const AS1 void*)gp, (AS3 void*)&VtS[g * 8], 16, 0, 0);
    }
    {
      int q = t >> 2, c16 = t & 3;
      const unsigned char* gp = mask + (size_t)b * SS * SS + (size_t)(q0 + q) * SS + kv0 + c16 * 16;
      __builtin_amdgcn_global_load_lds((const AS1 void*)gp, (AS3 void*)&MsB[t * 16], 16, 0, 0);
    }
    __syncthreads();

    f32x4 s[4];
#pragma unroll
    for (int nt = 0; nt < 4; ++nt) s[nt] = (f32x4){0.f, 0.f, 0.f, 0.f};
#pragma unroll
    for (int dc = 0; dc < 6; ++dc) {
#pragma unroll
      for (int nt = 0; nt < 4; ++nt) {
        int row = nt * 16 + fr;
        int wby = (dc * 64 + fq * 16) ^ ((fr & 7) << 4);
        bf16x8 kf = *(const bf16x8*)&KsS[row * 192 + (wby >> 1)];
        s[nt] = __builtin_amdgcn_mfma_f32_16x16x32_bf16(qf[dc], kf, s[nt], 0, 0, 0);
      }
    }

    float smat[4][4];
#pragma unroll
    for (int rg = 0; rg < 4; ++rg)
#pragma unroll
      for (int nt = 0; nt < 4; ++nt) {
        float v = s[nt][rg] * (1.f / 32.f);
        if (MsB[(wq * 16 + fq * 4 + rg) * 64 + nt * 16 + fr]) v = -1e9f;
        smat[nt][rg] = v;
      }

    float svm[4];
    int ok = 1;
#pragma unroll
    for (int rg = 0; rg < 4; ++rg) {
      svm[rg] = fmaxf(fmaxf(smat[0][rg], smat[1][rg]), fmaxf(smat[2][rg], smat[3][rg]));
      ok &= (svm[rg] <= m_r[rg] + 8.f) ? 1 : 0;
    }
    float p[4][4];
    if (__all(ok)) {
#pragma unroll
      for (int rg = 0; rg < 4; ++rg)
#pragma unroll
        for (int nt = 0; nt < 4; ++nt) {
          float pv = expf(smat[nt][rg] - m_r[rg]);
          p[nt][rg] = pv;
          l_r[rg] += pv;
        }
    } else {
#pragma unroll
      for (int rg = 0; rg < 4; ++rg) {
        float mx = svm[rg];
#pragma unroll
        for (int w2 = 1; w2 < 16; w2 <<= 1) mx = fmaxf(mx, __shfl_xor(mx, w2));
        float mnew = fmaxf(m_r[rg], mx);
        float alpha = expf(m_r[rg] - mnew);
        l_r[rg] *= alpha;
#pragma unroll
        for (int nt = 0; nt < 4; ++nt) {
          float pv = expf(smat[nt][rg] - mnew);
          p[nt][rg] = pv;
          l_r[rg] += pv;
        }
#pragma unroll
        for (int nt = 0; nt < 12; ++nt) cacc[nt][rg] *= alpha;
        m_r[rg] = mnew;
      }
    }

#pragma unroll
    for (int nt = 0; nt < 4; ++nt)
#pragma unroll
      for (int rg = 0; rg < 4; ++rg)
        myPs[(fq * 4 + rg) * 72 + nt * 16 + fr] = f2bf(p[nt][rg]);
    asm volatile("s_waitcnt lgkmcnt(0)" ::: "memory");

    bf16x8 pa[2];
#pragma unroll
    for (int kc = 0; kc < 2; ++kc)
      pa[kc] = *(const bf16x8*)&myPs[fr * 72 + kc * 32 + fq * 8];
#pragma unroll
    for (int nt = 0; nt < 12; ++nt) {
      int row = nt * 16 + fr;
#pragma unroll
      for (int kc = 0; kc < 2; ++kc) {
        int wby = (kc * 64 + fq * 16) ^ ((fr & 7) << 4);
        bf16x8 vf = *(const bf16x8*)&VtS[row * 64 + (wby >> 1)];
        cacc[nt] = __builtin_amdgcn_mfma_f32_16x16x32_bf16(pa[kc], vf, cacc[nt], 0, 0, 0);
      }
    }
  }

#pragma unroll
  for (int rg = 0; rg < 4; ++rg) {
    float ls = l_r[rg];
#pragma unroll
    for (int w2 = 1; w2 < 16; w2 <<= 1) ls += __shfl_xor(ls, w2);
    l_r[rg] = ls;
  }

  float* op = opart + (size_t)kvh * (BB * SS * DD);
#pragma unroll
  for (int rg = 0; rg < 4; ++rg) {
    int row = b * SS + qrow + fq * 4 + rg;
    if (fr == 0) {
      mlws[(((size_t)kvh * (BB * SS) + row) * 4 + h) * 2 + 0] = m_r[rg];
      mlws[(((size_t)kvh * (BB * SS) + row) * 4 + h) * 2 + 1] = l_r[rg];
    }
#pragma unroll
    for (int nt = 0; nt < 12; ++nt)
      op[(size_t)row * DD + h * DQ + nt * 16 + fr] = cacc[nt][rg];
  }
}

// ==================== flash-merge of the two kv halves ====================
__global__ __launch_bounds__(256) void k_amerge(
    const float* __restrict__ opart, const float* __restrict__ mlws,
    short* __restrict__ ctxb)
{
  int row = blockIdx.x;
  int t = threadIdx.x;
  __shared__ float a0s[4], a1s[4], linvs[4];
  if (t < 4) {
    float m0 = mlws[(((size_t)row) * 4 + t) * 2 + 0];
    float l0 = mlws[(((size_t)row) * 4 + t) * 2 + 1];
    float m1 = mlws[(((size_t)(BB * SS) + row) * 4 + t) * 2 + 0];
    float l1 = mlws[(((size_t)(BB * SS) + row) * 4 + t) * 2 + 1];
    float m = fmaxf(m0, m1);
    float a0 = expf(m0 - m), a1 = expf(m1 - m);
    a0s[t] = a0; a1s[t] = a1;
    linvs[t] = 1.f / (l0 * a0 + l1 * a1);
  }
  __syncthreads();
#pragma unroll
  for (int j = 0; j < 3; ++j) {
    int d = t + j * 256;
    int h = d / DQ;
    float o0 = opart[(size_t)row * DD + d];
    float o1 = opart[(size_t)(BB * SS) * DD + (size_t)row * DD + d];
    ctxb[(size_t)row * DD + d] = f2bf((o0 * a0s[h] + o1 * a1s[h]) * linvs[h]);
  }
}

// ==================== cls head from bf16 ff (f32 weights/accum) ====================
__global__ void k_cls(const short* __restrict__ ffb, const float* __restrict__ Wc,
                      const float* __restrict__ bc, float* __restrict__ out)
{
  int t = threadIdx.x;
  int o = t >> 3, l8 = t & 7;
  int b = o >> 1, cN = o & 1;
  float s = 0.f;
  for (int d = l8; d < DD; d += 8)
    s += bf2f(ffb[(size_t)(b * SS) * DD + d]) * Wc[d * 2 + cN];
#pragma unroll
  for (int w = 1; w < 8; w <<= 1) s += __shfl_xor(s, w);
  if (l8 == 0) out[o] = s + bc[cN];
}

// ==========================================================================
extern "C" void kernel_launch(void* const* d_in, const int* in_sizes, int n_in,
                              void* d_out, int out_size, void* d_ws, size_t ws_size,
                              hipStream_t stream)
{
  const int*           ids  = (const int*)d_in[0];
  const unsigned char* mask = (const unsigned char*)d_in[1];
  const float* tok  = (const float*)d_in[2];
  const float* seg  = (const float*)d_in[3];
  const float* pos  = (const float*)d_in[4];
  const float* ln_g = (const float*)d_in[5];
  const float* ln_b = (const float*)d_in[6];
  const float* Wq   = (const float*)d_in[7];
  const float* bq   = (const float*)d_in[8];
  const float* Wk   = (const float*)d_in[9];
  const float* bk   = (const float*)d_in[10];
  const float* Wv   = (const float*)d_in[11];
  const float* bv   = (const float*)d_in[12];
  const float* Wo   = (const float*)d_in[13];
  const float* bo   = (const float*)d_in[14];
  const float* W1   = (const float*)d_in[15];
  const float* b1   = (const float*)d_in[16];
  const float* W2   = (const float*)d_in[17];
  const float* b2   = (const float*)d_in[18];
  const float* Wtok = (const float*)d_in[19];
  const float* btok = (const float*)d_in[20];
  const float* Wcls = (const float*)d_in[21];
  const float* bcls = (const float*)d_in[22];

  // -------- workspace regions (float units), aliasing by lifetime --------
  float* ws = (float*)d_ws;
  short* qkvb = (short*)(ws);                          // [4096][2304] bf16, [0, 4718592)
  short* Bt1  = (short*)(ws);                          // [3072][768]  bf16 (step 7)
  short* ff1b = (short*)(ws + 1310720);                // [4096][3072] bf16 (step 7)
  short* Btt  = (short*)(ws);                          // [30592][768] bf16 (step 9)
  float* opart = ws + 4718592;                         // [2][4096][768] f32 (attn only)
  float* mlws  = ws + 4718592 + 6291456;               // [2][4096][4][2] f32
  short* vt   = (short*)(ws + 11747328);               // [768][4096] bf16
  short* Btwo = (short*)(ws + 11747328);
  short* Bt2  = (short*)(ws + 11747328);
  short* ctxb = (short*)(ws + 13320192);               // [4096][768] bf16
  short* ffb  = (short*)(ws + 13320192);
  short* xb   = (short*)(ws + 14893056);               // [4096][768] bf16
  short* attb = (short*)(ws + 14893056);
  short* Btqkv = (short*)(ws + 16465920);              // [2304][768] bf16
  float* bqkv = ws + 17350656;

  float* cls    = (float*)d_out;
  float* tokout = (float*)d_out + 8;

  // 1. embeddings + LayerNorm
  k_embed_ln<<<BB * SS, 256, 0, stream>>>(ids, tok, seg, pos, ln_g, ln_b, xb);

  // 2. QKV weight pack + bias pack
  k_packqkv<<<dim3(6, 24, 12), 256, 0, stream>>>(Wq, Wk, Wv, Btqkv);
  k_bpack<<<9, 256, 0, stream>>>(bq, bk, bv, bqkv);

  // 3. fused QKV GEMM -> qkvb bf16 [4096][2304]
  k_gemm_bf16<1, 0><<<8 * 4 * 18, 256, 0, stream>>>(xb, Btqkv, bqkv, qkvb, 2304, DD, 18);

  // 4. V transpose -> vt [768][4096]
  k_vtrans<<<dim3(128, 24), 256, 0, stream>>>(qkvb, vt);

  // 5. wide MFMA attention (kv-split x2) + merge -> ctxb
  k_attn<<<512, 256, 0, stream>>>(qkvb, vt, mask, opart, mlws);
  k_amerge<<<BB * SS, 256, 0, stream>>>(opart, mlws, ctxb);

  // 6. Wo GEMM -> attb
  k_wtrans<<<dim3(24, 24), 256, 0, stream>>>(Wo, Btwo, DD, DD);
  k_gemm_bf16<1, 0><<<8 * 4 * 6, 256, 0, stream>>>(ctxb, Btwo, bo, attb, DD, DD, 6);

  // 7. FFN
  k_wtrans<<<dim3(96, 24), 256, 0, stream>>>(W1, Bt1, DFF, DD);
  k_gemm_bf16<1, 1><<<8 * 4 * 24, 256, 0, stream>>>(attb, Bt1, b1, ff1b, DFF, DD, 24);
  k_wtrans<<<dim3(24, 96), 256, 0, stream>>>(W2, Bt2, DD, DFF);
  k_gemm_bf16<1, 0><<<8 * 4 * 6, 256, 0, stream>>>(ff1b, Bt2, b2, ffb, DD, DFF, 6);

  // 8. cls head (bf16 ff, f32 weights/accum)
  k_cls<<<1, 64, 0, stream>>>(ffb, Wcls, bcls, cls);

  // 9. vocab projection (r13-proven 128^2 ring-3)
  k_wtrans<<<dim3(NPAD / 32, 24), 256, 0, stream>>>(Wtok, Btt, NVOC, DD);
  k_gemm_bf16<0, 0><<<8 * 4 * 239, 256, 0, stream>>>(ffb, Btt, btok, tokout, NVOC, DD, 239);
}